// Round 15
// baseline (215.079 us; speedup 1.0000x reference)
//
#include <hip/hip_runtime.h>
#include <math.h>

typedef unsigned short u16;
typedef __attribute__((ext_vector_type(8))) short bffrag;   // 8 bf16 MFMA operand
typedef __attribute__((ext_vector_type(4))) float f32x4;    // MFMA accumulator
typedef __attribute__((ext_vector_type(4))) unsigned short us4;
typedef __attribute__((ext_vector_type(8))) unsigned short us8;

#define SCALE_QK (1.0f/32.0f)

// fp32 -> bf16 round-to-nearest-even (bit trick, NaN-free inputs)
__device__ __forceinline__ u16 f2bf(float f) {
    unsigned u = __builtin_bit_cast(unsigned, f);
    u += 0x7fffu + ((u >> 16) & 1u);
    return (u16)(u >> 16);
}
__device__ __forceinline__ float bf2f(u16 v) {
    unsigned u = ((unsigned)v) << 16;
    return __builtin_bit_cast(float, u);
}

__device__ __forceinline__ void gld16(const u16* g, u16* l) {
    __builtin_amdgcn_global_load_lds(
        (const __attribute__((address_space(1))) void*)g,
        (__attribute__((address_space(3))) void*)l, 16, 0, 0);
}

// ---------------- router (fp32, exact) + c1 partial blocks ----------------
__global__ __launch_bounds__(256) void router_c1(const float* __restrict__ X,
                                                 const float* __restrict__ sW,
                                                 float* __restrict__ part,
                                                 const float* __restrict__ Wff,
                                                 const float* __restrict__ bv,
                                                 float* __restrict__ cpart) {
    int bid = blockIdx.x;
    if (bid < 256) {
        int e = bid >> 5;
        int r = bid & 31;
        int d = (r & 3) * 256 + threadIdx.x;
        int h0 = (r >> 2) * 128;
        const float* W = Wff + ((size_t)e << 20) + (size_t)h0 * 1024 + d;
        const float* bvp = bv + e * 1024 + h0;
        float s = 0.f;
        #pragma unroll 4
        for (int h = 0; h < 128; ++h) s += bvp[h] * W[(size_t)h * 1024];
        cpart[(e * 8 + (r >> 2)) * 1024 + d] = s;
        return;
    }
    int rbid = bid - 256;
    float acc[32];
    #pragma unroll
    for (int a = 0; a < 32; ++a) acc[a] = 0.f;
    int tid = rbid * 256 + threadIdx.x;
    #pragma unroll
    for (int q = 0; q < 4; ++q) {
        int i = tid + q * 262144;
        float4 w0 = *(const float4*)(sW + (size_t)i * 8);
        float4 w1 = *(const float4*)(sW + (size_t)i * 8 + 4);
        #pragma unroll
        for (int b = 0; b < 4; ++b) {
            float x = X[((size_t)b << 20) + i];
            acc[b*8+0] += x * w0.x; acc[b*8+1] += x * w0.y;
            acc[b*8+2] += x * w0.z; acc[b*8+3] += x * w0.w;
            acc[b*8+4] += x * w1.x; acc[b*8+5] += x * w1.y;
            acc[b*8+6] += x * w1.z; acc[b*8+7] += x * w1.w;
        }
    }
    __shared__ float wsum[4][32];
    int lane = threadIdx.x & 63, wv = threadIdx.x >> 6;
    #pragma unroll
    for (int a = 0; a < 32; ++a) {
        float v = acc[a];
        #pragma unroll
        for (int off = 32; off; off >>= 1) v += __shfl_down(v, off, 64);
        if (lane == 0) wsum[wv][a] = v;
    }
    __syncthreads();
    int t = threadIdx.x;
    if (t < 32)
        part[(size_t)t * 1024 + rbid] = wsum[0][t] + wsum[1][t] + wsum[2][t] + wsum[3][t];
}

__global__ __launch_bounds__(256) void router_final(const float* __restrict__ part,
                                                    const float* __restrict__ sb,
                                                    int* __restrict__ sel_need) {
    __shared__ float ps[32][8];
    __shared__ float lg[32];
    int t = threadIdx.x, a = t >> 3, c = t & 7;
    {
        float s = 0.f;
        const float* p = part + (size_t)a * 1024 + c * 128;
        for (int i = 0; i < 128; ++i) s += p[i];
        ps[a][c] = s;
    }
    __syncthreads();
    if (t < 32) {
        float v = 0.f;
        #pragma unroll
        for (int j = 0; j < 8; ++j) v += ps[t][j];
        lg[t] = v + sb[t & 7];
    }
    __syncthreads();
    if (t < 4) {
        int base = t * 8;
        int e1 = 0; float v1 = lg[base];
        for (int e = 1; e < 8; ++e) { if (lg[base + e] > v1) { v1 = lg[base + e]; e1 = e; } }
        int e2 = -1; float v2 = -INFINITY;
        for (int e = 0; e < 8; ++e) {
            if (e == e1) continue;
            if (lg[base + e] > v2) { v2 = lg[base + e]; e2 = e; }
        }
        sel_need[t * 2] = e1; sel_need[t * 2 + 1] = e2;
    }
    __syncthreads();
    if (t < 8) {
        int need = 0;
        for (int j = 0; j < 8; ++j) need |= (sel_need[j] == t);
        sel_need[8 + t] = need;
    }
}

// ---------------- unified convert (r14 proven) ----------------
__global__ __launch_bounds__(256) void cvt_all(const float* __restrict__ Wq,
                                               const float* __restrict__ Wk,
                                               const float* __restrict__ Wff,
                                               const float* __restrict__ X,
                                               const float* __restrict__ Wv,
                                               const int* __restrict__ sel_need,
                                               u16* __restrict__ WqT, u16* __restrict__ WkT,
                                               u16* __restrict__ WffT,
                                               u16* __restrict__ Xb, u16* __restrict__ WvB) {
    int z = blockIdx.z;
    int R0 = blockIdx.y * 128, C0 = blockIdx.x * 128;
    int t = threadIdx.x;
    if (z < 24) {
        int type = z >> 3, e = z & 7;
        if (!sel_need[8 + e]) return;
        const float* src = (type == 0 ? Wq : type == 1 ? Wk : Wff) + ((size_t)e << 20);
        u16* dst = (type == 0 ? WqT : type == 1 ? WkT : WffT) + ((size_t)e << 20);
        __shared__ u16 lt[128 * 136];
        int r = t >> 4;
        int c8 = (t & 15) * 8;
        #pragma unroll
        for (int it = 0; it < 8; ++it) {
            int row = it * 16 + r;
            const float* sp = src + (size_t)(R0 + row) * 1024 + C0 + c8;
            float4 a = *(const float4*)sp;
            float4 b2 = *(const float4*)(sp + 4);
            us8 o;
            o[0] = f2bf(a.x); o[1] = f2bf(a.y); o[2] = f2bf(a.z); o[3] = f2bf(a.w);
            o[4] = f2bf(b2.x); o[5] = f2bf(b2.y); o[6] = f2bf(b2.z); o[7] = f2bf(b2.w);
            int cs = c8 ^ (((row >> 3) & 7) << 3);
            *(us8*)&lt[row * 136 + cs] = o;
        }
        __syncthreads();
        int dd = (t & 15) * 8;
        int hh = t >> 4;
        #pragma unroll
        for (int it = 0; it < 8; ++it) {
            int cr = it * 16 + hh;
            us8 o;
            #pragma unroll
            for (int j = 0; j < 8; ++j) {
                int row = dd + j;
                int cs = cr ^ (((row >> 3) & 7) << 3);
                o[j] = lt[row * 136 + cs];
            }
            *(us8*)(dst + (size_t)(C0 + cr) * 1024 + R0 + dd) = o;
        }
    } else {
        const float* src; u16* dst;
        if (z < 28) {
            int b = z - 24;
            src = X + ((size_t)b << 20);  dst = Xb + ((size_t)b << 20);
        } else {
            int e = z - 28;
            if (!sel_need[8 + e]) return;
            src = Wv + ((size_t)e << 20);  dst = WvB + ((size_t)e << 20);
        }
        int r = t >> 4;
        int c8 = (t & 15) * 8;
        #pragma unroll
        for (int it = 0; it < 8; ++it) {
            int row = R0 + it * 16 + r;
            const float* sp = src + (size_t)row * 1024 + C0 + c8;
            float4 a = *(const float4*)sp;
            float4 b2 = *(const float4*)(sp + 4);
            us8 o;
            o[0] = f2bf(a.x); o[1] = f2bf(a.y); o[2] = f2bf(a.z); o[3] = f2bf(a.w);
            o[4] = f2bf(b2.x); o[5] = f2bf(b2.y); o[6] = f2bf(b2.z); o[7] = f2bf(b2.w);
            *(us8*)(dst + (size_t)row * 1024 + C0 + c8) = o;
        }
    }
}

// ============ 128x128 BK=64 core, 2 blocks/CU (64 KB LDS), counted-vmcnt fat 2-phase ============
// Stage one full 128x64 operand tile (4 gld16/thread), inverse-swizzled global source.
__device__ __forceinline__ void stage_t2(const u16* g, int ld, u16* ldst, int tid) {
    #pragma unroll
    for (int it = 0; it < 4; ++it) {
        int u = it * 256 + tid;
        int row = u >> 3;
        int j = ((u ^ row) & 7) * 8;           // global slot = lds_slot ^ (row&7)
        gld16(g + (size_t)row * ld + j, ldst + u * 8);
    }
}

template<int P, bool LASTVM>
__device__ __forceinline__ void phase2(const u16* Ac, const bffrag (&bfr)[4][2],
                                       f32x4 (&acc)[4][4], int rb, int l15, int x0,
                                       const u16* sg, int sld, u16* sdst, int tid) {
    bffrag af[2][2];
    #pragma unroll
    for (int mm = 0; mm < 2; ++mm) {
        int r = (rb + (P * 2 + mm) * 16 + l15) * 64;
        af[mm][0] = *(const bffrag*)(Ac + r + x0);
        af[mm][1] = *(const bffrag*)(Ac + r + (x0 ^ 32));
    }
    __builtin_amdgcn_sched_barrier(0);
    stage_t2(sg, sld, sdst, tid);
    __builtin_amdgcn_sched_barrier(0);
    __builtin_amdgcn_s_barrier();
    asm volatile("s_waitcnt lgkmcnt(0)" ::: "memory");
    __builtin_amdgcn_sched_barrier(0);
    __builtin_amdgcn_s_setprio(1);
    #pragma unroll
    for (int ks = 0; ks < 2; ++ks)
        #pragma unroll
        for (int mm = 0; mm < 2; ++mm)
            #pragma unroll
            for (int nn = 0; nn < 4; ++nn)
                acc[P*2+mm][nn] = __builtin_amdgcn_mfma_f32_16x16x32_bf16(
                    af[mm][ks], bfr[nn][ks], acc[P*2+mm][nn], 0, 0, 0);
    __builtin_amdgcn_s_setprio(0);
    __builtin_amdgcn_sched_barrier(0);
    if (LASTVM) asm volatile("s_waitcnt vmcnt(4)" ::: "memory");
    __builtin_amdgcn_s_barrier();
}

// C[m][n] = sum_k A[m][k]*B[n][k].  4 waves (2x2), per-wave 64x64 (acc[4][4]).
// LDS 64 KB: buf[2] x {A 128x64 | B 128x64}.
// Per K-tile: P0 {af m0,m1 || stage A(t+1)->An} ; P1 {af m2,m3 || stage B(t+2)->Bc, vmcnt(4)}.
__device__ __forceinline__ void gemm2(const u16* __restrict__ A, int lda,
                                      const u16* __restrict__ B, int ldb,
                                      int K, int m0, int n0, f32x4 (&acc)[4][4]) {
    __shared__ u16 lds[32768];                 // 64 KB
    const int tid = threadIdx.x, l = tid & 63, wid = tid >> 6;
    const int rb = (wid >> 1) * 64;            // wave A-row base
    const int cb = (wid & 1) * 64;             // wave B-row base
    const int l15 = l & 15;
    const int x0 = (((l >> 4) ^ (l & 7)) * 8);
    const int nt = K >> 6;

    const u16* Ag = A + (size_t)m0 * lda;
    const u16* Bg = B + (size_t)n0 * ldb;

    // prologue: A(0)->buf0.A, B(0)->buf0.B, B(1)->buf1.B  (12 loads/thread)
    stage_t2(Ag, lda, lds, tid);
    stage_t2(Bg, ldb, lds + 8192, tid);
    {
        int kb1 = (1 < nt ? 1 : nt - 1) << 6;
        stage_t2(Bg + kb1, ldb, lds + 16384 + 8192, tid);
    }
    asm volatile("s_waitcnt vmcnt(4)" ::: "memory");   // drain A(0),B(0); keep B(1)
    __builtin_amdgcn_s_barrier();

    for (int t7 = 0; t7 < nt; ++t7) {
        const int cur = t7 & 1;
        u16* Ac = lds + cur * 16384;
        u16* Bc = Ac + 8192;
        u16* An = lds + (cur ^ 1) * 16384;
        int ka = (t7 + 1 < nt ? t7 + 1 : nt - 1) << 6;
        int kb = (t7 + 2 < nt ? t7 + 2 : nt - 1) << 6;

        bffrag bfr[4][2];
        #pragma unroll
        for (int nn = 0; nn < 4; ++nn) {
            int r = (cb + nn * 16 + l15) * 64;
            bfr[nn][0] = *(const bffrag*)(Bc + r + x0);
            bfr[nn][1] = *(const bffrag*)(Bc + r + (x0 ^ 32));
        }
        phase2<0, false>(Ac, bfr, acc, rb, l15, x0, Ag + ka, lda, An, tid);
        phase2<1, true >(Ac, bfr, acc, rb, l15, x0, Bg + kb, ldb, Bc, tid);
    }
}

__device__ __forceinline__ void zero_acc(f32x4 (&acc)[4][4]) {
    #pragma unroll
    for (int m = 0; m < 4; ++m)
        #pragma unroll
        for (int n = 0; n < 4; ++n)
            #pragma unroll
            for (int i = 0; i < 4; ++i) acc[m][n][i] = 0.f;
}

// epilogue for the 2x2-wave cores (gemm2 / gemm_ds share wave layout)
__device__ __forceinline__ void epi4_bf16s(u16* __restrict__ C, int ldc, float scale,
                                           const f32x4 (&acc)[4][4],
                                           const float* __restrict__ biasN,
                                           int m0, int n0) {
    const int tid = threadIdx.x, lane = tid & 63, wv = tid >> 6;
    const int wr = (wv >> 1) * 64, wc = (wv & 1) * 64;
    const int l15 = lane & 15, l4 = (lane >> 4) * 4;
    #pragma unroll
    for (int m = 0; m < 4; ++m)
        #pragma unroll
        for (int n = 0; n < 4; ++n) {
            int col = n0 + wc + n * 16 + l15;
            float bn = biasN ? biasN[col] : 0.f;
            #pragma unroll
            for (int i = 0; i < 4; ++i) {
                int row = m0 + wr + m * 16 + l4 + i;
                C[(size_t)row * ldc + col] = f2bf(acc[m][n][i] * scale + bn);
            }
        }
}

__device__ __forceinline__ void epi4_f32(float* __restrict__ C, int ldc, int m0, int n0,
                                         const f32x4 (&acc)[4][4],
                                         const float* __restrict__ bias1) {
    const int tid = threadIdx.x, lane = tid & 63, wv = tid >> 6;
    const int wr = (wv >> 1) * 64, wc = (wv & 1) * 64;
    const int l15 = lane & 15, l4 = (lane >> 4) * 4;
    #pragma unroll
    for (int m = 0; m < 4; ++m)
        #pragma unroll
        for (int n = 0; n < 4; ++n) {
            int col = n0 + wc + n * 16 + l15;
            float bn = bias1 ? bias1[col] : 0.f;
            #pragma unroll
            for (int i = 0; i < 4; ++i) {
                int row = m0 + wr + m * 16 + l4 + i;
                C[(size_t)row * ldc + col] = acc[m][n][i] + bn;
            }
        }
}

// XCD-clustered decode for 1024-block grids: XCD k serves z = k and z = k+8.
__device__ __forceinline__ void xcd_decode2(int f, int& z, int& m0, int& n0) {
    int xcd = f & 7, slot = f >> 3;        // slot 0..127
    z = xcd + ((slot >> 6) << 3);
    int idx = slot & 63;
    m0 = (idx >> 3) * 128;
    n0 = (idx & 7) * 128;
}

// D1: z 0..15, w=z>>3 (0=Q,1=K), bs=z&7
__global__ __launch_bounds__(256) void mfma8_qk(const u16* __restrict__ Xb,
        const u16* __restrict__ WqT, const u16* __restrict__ WkT,
        const float* __restrict__ bq, const float* __restrict__ bk,
        const int* __restrict__ sel, u16* __restrict__ Qb, u16* __restrict__ Kb) {
    int z, m0, n0;
    xcd_decode2(blockIdx.x, z, m0, n0);
    int w = z >> 3, bs = z & 7;
    int b = bs >> 1, e = sel[bs];
    f32x4 acc[4][4]; zero_acc(acc);
    gemm2(Xb + ((size_t)b << 20), 1024, (w ? WkT : WqT) + ((size_t)e << 20), 1024,
          1024, m0, n0, acc);
    epi4_bf16s((w ? Kb : Qb) + ((size_t)bs << 20), 1024, 1.0f, acc,
               (w ? bk : bq) + e * 1024, m0, n0);
}

// D2: z<8 scores->Sb (bf16, scaled); z 8..15 wvf halves -> P0b/P1b (bf16)
__global__ __launch_bounds__(256) void mfma8_sw(const u16* __restrict__ Qb,
        const u16* __restrict__ Kb, const u16* __restrict__ WffT,
        const u16* __restrict__ WvB, const int* __restrict__ sel,
        u16* __restrict__ Sb, u16* __restrict__ P0b, u16* __restrict__ P1b) {
    int z, m0, n0;
    xcd_decode2(blockIdx.x, z, m0, n0);
    f32x4 acc[4][4]; zero_acc(acc);
    if (z < 8) {
        gemm2(Qb + ((size_t)z << 20), 1024, Kb + ((size_t)z << 20), 1024, 1024, m0, n0, acc);
        epi4_bf16s(Sb + ((size_t)z << 20), 1024, SCALE_QK, acc, nullptr, m0, n0);
    } else {
        int h = ((z & 7) >= 4), b = z & 3, e = sel[b * 2 + h];
        gemm2(WffT + ((size_t)e << 20), 1024, WvB + ((size_t)e << 20), 1024, 1024, m0, n0, acc);
        epi4_bf16s((h ? P1b : P0b) + ((size_t)b << 20), 1024, 1.0f, acc, nullptr, m0, n0);
    }
}

// Wvfsum[b] = bf16(P0b[b] + P1b[b]);  bids >= 2048: ybias blocks (cpart-based)
__global__ __launch_bounds__(256) void wvfadd(const u16* __restrict__ P0b,
                                              const u16* __restrict__ P1b,
                                              u16* __restrict__ W,
                                              const float* __restrict__ cpart,
                                              const float* __restrict__ bff,
                                              const int* __restrict__ sel,
                                              float* __restrict__ ybias) {
    int bid = blockIdx.x;
    if (bid >= 2048) {
        int r = bid - 2048;
        int b = r >> 2;
        int d = (r & 3) * 256 + threadIdx.x;
        int e0 = sel[b * 2], e1 = sel[b * 2 + 1];
        float c0 = 0.f, c1v = 0.f;
        #pragma unroll
        for (int hc = 0; hc < 8; ++hc) {
            c0  += cpart[(e0 * 8 + hc) * 1024 + d];
            c1v += cpart[(e1 * 8 + hc) * 1024 + d];
        }
        ybias[b * 1024 + d] = 2.f * (c0 + c1v) + bff[e0 * 1024 + d] + bff[e1 * 1024 + d];
        return;
    }
    size_t i = (size_t)(bid * 256 + threadIdx.x) * 8;
    us8 a = *(const us8*)(P0b + i);
    us8 b = *(const us8*)(P1b + i);
    us8 o;
    #pragma unroll
    for (int j = 0; j < 8; ++j) o[j] = f2bf(bf2f(a[j]) + bf2f(b[j]));
    *(us8*)(W + i) = o;
}

// ---------------- 2-phase 128x128 BK=32 core (tail GEMMs; proven) ----------------
__device__ __forceinline__ void stage_tile(const u16* a0, const u16* a1,
                                           const u16* b0, const u16* b1,
                                           u16* sa, u16* sb, int tid) {
    gld16(a0, &sa[tid * 8]);
    gld16(a1, &sa[2048 + tid * 8]);
    gld16(b0, &sb[tid * 8]);
    gld16(b1, &sb[2048 + tid * 8]);
}

__device__ __forceinline__ void gemm_ds(const u16* __restrict__ A, int lda,
                                        const u16* __restrict__ B, int ldb,
                                        int K, int m0, int n0, f32x4 (&acc)[4][4]) {
    __shared__ u16 sA[2][4096];
    __shared__ u16 sB[2][4096];
    const int tid = threadIdx.x, lane = tid & 63, wv = tid >> 6;
    const int wr = (wv >> 1) * 64, wc = (wv & 1) * 64;
    const int l15 = lane & 15, lk = (lane >> 4) * 8;
    const int r0 = tid >> 2, k8 = (tid & 3) * 8;

    const u16* a0 = A + (size_t)(m0 + r0) * lda + k8;
    const u16* a1 = A + (size_t)(m0 + 64 + r0) * lda + k8;
    const u16* b0 = B + (size_t)(n0 + r0) * ldb + k8;
    const u16* b1 = B + (size_t)(n0 + 64 + r0) * ldb + k8;

    stage_tile(a0, a1, b0, b1, sA[0], sB[0], tid);
    __syncthreads();

    const int nt = K >> 5;
    for (int t = 0; t < nt; ++t) {
        const int cur = t & 1;
        if (t + 1 < nt) {
            int k0 = (t + 1) << 5;
            stage_tile(a0 + k0, a1 + k0, b0 + k0, b1 + k0, sA[cur ^ 1], sB[cur ^ 1], tid);
        }
        bffrag av[4], bf[4];
        #pragma unroll
        for (int m = 0; m < 4; ++m)
            av[m] = *reinterpret_cast<const bffrag*>(&sA[cur][(wr + m * 16 + l15) * 32 + lk]);
        #pragma unroll
        for (int n = 0; n < 4; ++n)
            bf[n] = *reinterpret_cast<const bffrag*>(&sB[cur][(wc + n * 16 + l15) * 32 + lk]);
        #pragma unroll
        for (int m = 0; m < 4; ++m)
            #pragma unroll
            for (int n = 0; n < 4; ++n)
                acc[m][n] = __builtin_amdgcn_mfma_f32_16x16x32_bf16(av[m], bf[n], acc[m][n], 0, 0, 0);
        __syncthreads();
    }
}

// ---------------- merged: Mt GEMM (bids 0..255) + softmax-combine (bids 256..4351) ----------------
__global__ __launch_bounds__(256) void sm_mt(const u16* __restrict__ Sb, u16* __restrict__ Ab,
        const u16* __restrict__ Wvfsum, const u16* __restrict__ Xb, u16* __restrict__ Mtb) {
    int bid = blockIdx.x;
    if (bid < 256) {
        int b = bid >> 6, m0 = ((bid >> 3) & 7) * 128, n0 = (bid & 7) * 128;
        f32x4 acc[4][4]; zero_acc(acc);
        gemm_ds(Wvfsum + ((size_t)b << 20), 1024, Xb + ((size_t)b << 20), 1024, 1024, m0, n0, acc);
        epi4_bf16s(Mtb + ((size_t)b << 20), 1024, 1.0f, acc, nullptr, m0, n0);
        return;
    }
    int bs = bid - 256, b = bs >> 10, s = bs & 1023;
    const u16* S0 = Sb + ((size_t)(b * 2) << 20) + (size_t)s * 1024;
    const u16* S1 = S0 + (1u << 20);
    int t = threadIdx.x, lane = t & 63, wv = t >> 6;
    us4 xv0 = *(const us4*)(S0 + t * 4);
    us4 xv1 = *(const us4*)(S1 + t * 4);
    float x0[4], x1[4];
    #pragma unroll
    for (int j = 0; j < 4; ++j) { x0[j] = bf2f(xv0[j]); x1[j] = bf2f(xv1[j]); }
    float m0 = fmaxf(fmaxf(x0[0], x0[1]), fmaxf(x0[2], x0[3]));
    float m1 = fmaxf(fmaxf(x1[0], x1[1]), fmaxf(x1[2], x1[3]));
    #pragma unroll
    for (int off = 32; off; off >>= 1) {
        m0 = fmaxf(m0, __shfl_xor(m0, off, 64));
        m1 = fmaxf(m1, __shfl_xor(m1, off, 64));
    }
    __shared__ float wred[4][4];
    if (lane == 0) { wred[wv][0] = m0; wred[wv][1] = m1; }
    __syncthreads();
    m0 = fmaxf(fmaxf(wred[0][0], wred[1][0]), fmaxf(wred[2][0], wred[3][0]));
    m1 = fmaxf(fmaxf(wred[0][1], wred[1][1]), fmaxf(wred[2][1], wred[3][1]));
    float e0[4], e1[4];
    #pragma unroll
    for (int j = 0; j < 4; ++j) { e0[j] = __expf(x0[j] - m0); e1[j] = __expf(x1[j] - m1); }
    float s0 = e0[0] + e0[1] + e0[2] + e0[3];
    float s1 = e1[0] + e1[1] + e1[2] + e1[3];
    #pragma unroll
    for (int off = 32; off; off >>= 1) {
        s0 += __shfl_xor(s0, off, 64);
        s1 += __shfl_xor(s1, off, 64);
    }
    if (lane == 0) { wred[wv][2] = s0; wred[wv][3] = s1; }
    __syncthreads();
    s0 = wred[0][2] + wred[1][2] + wred[2][2] + wred[3][2];
    s1 = wred[0][3] + wred[1][3] + wred[2][3] + wred[3][3];
    float r0 = 1.f / s0, r1 = 1.f / s1;
    us4 o;
    #pragma unroll
    for (int j = 0; j < 4; ++j) o[j] = f2bf(e0[j] * r0 + e1[j] * r1);
    *(us4*)(Ab + ((size_t)b << 20) + (size_t)s * 1024 + t * 4) = o;
}

// y[b][s][d2] = sum_t A[b][s][t] * Mt[b][d2][t] + ybias[b][d2]
__global__ __launch_bounds__(256) void mfma_y(const u16* __restrict__ Abf,
        const u16* __restrict__ Mtb, const float* __restrict__ ybias,
        float* __restrict__ y) {
    int b = blockIdx.z;
    int m0 = blockIdx.y * 128, n0 = blockIdx.x * 128;
    f32x4 acc[4][4]; zero_acc(acc);
    gemm_ds(Abf + ((size_t)b << 20), 1024, Mtb + ((size_t)b << 20), 1024, 1024, m0, n0, acc);
    epi4_f32(y + ((size_t)b << 20), 1024, m0, n0, acc, ybias + b * 1024);
}

// ---------------- launcher ----------------
extern "C" void kernel_launch(void* const* d_in, const int* in_sizes, int n_in,
                              void* d_out, int out_size, void* d_ws, size_t ws_size,
                              hipStream_t stream) {
    const float* X   = (const float*)d_in[0];
    const float* sW  = (const float*)d_in[2];
    const float* sb  = (const float*)d_in[3];
    const float* Wq  = (const float*)d_in[4];
    const float* bq  = (const float*)d_in[5];
    const float* Wk  = (const float*)d_in[6];
    const float* bk  = (const float*)d_in[7];
    const float* Wv  = (const float*)d_in[8];
    const float* bv  = (const float*)d_in[9];
    const float* Wff = (const float*)d_in[10];
    const float* bff = (const float*)d_in[11];
    float* y = (float*)d_out;

    char* w = (char*)d_ws;
    float* part  = (float*)w;                  // 128 KB
    float* cpart = (float*)(w + (1u << 17));   // 256 KB (concurrent with part)
    int*   sel   = (int*)(w + 393216);         // at 384 KB
    float* ybias = (float*)(w + 393216 + 256); // 16 KB
    u16* base = (u16*)(w + (1u << 19));        // at 512 KB
    u16* Xb   = base;                          // 8 MB
    u16* WqT  = Xb   + (4u << 20);             // 16 MB  [Abf overlay]
    u16* WkT  = WqT  + (8u << 20);             // 16 MB  [Mtb overlay]
    u16* WffT = WkT  + (8u << 20);             // 16 MB
    u16* WvB  = WffT + (8u << 20);             // 16 MB
    u16* Qb   = WvB  + (8u << 20);             // 16 MB  [Wvfsum overlay]
    u16* Kb   = Qb   + (8u << 20);             // 16 MB
    u16* Sb   = Kb   + (8u << 20);             // 16 MB (bf16 scores, 8 x 1M)
    u16* P0b  = Sb   + (8u << 20);             // 8 MB
    u16* P1b  = P0b  + (4u << 20);             // 8 MB
    u16* Abf    = WqT;   // WqT dead after mfma8_qk
    u16* Mtb    = WkT;   // WkT dead after mfma8_qk
    u16* Wvfsum = Qb;    // Qb dead after mfma8_sw

    router_c1<<<1280, 256, 0, stream>>>(X, sW, part, Wff, bv, cpart);
    router_final<<<1, 256, 0, stream>>>(part, sb, sel);
    cvt_all<<<dim3(8, 8, 36), 256, 0, stream>>>(Wq, Wk, Wff, X, Wv, sel,
                                                WqT, WkT, WffT, Xb, WvB);

    mfma8_qk<<<1024, 256, 0, stream>>>(Xb, WqT, WkT, bq, bk, sel, Qb, Kb);
    mfma8_sw<<<1024, 256, 0, stream>>>(Qb, Kb, WffT, WvB, sel, Sb, P0b, P1b);
    wvfadd<<<2064, 256, 0, stream>>>(P0b, P1b, Wvfsum, cpart, bff, sel, ybias);
    sm_mt<<<4352, 256, 0, stream>>>(Sb, Abf, Wvfsum, Xb, Mtb);
    mfma_y<<<dim3(8, 8, 4), 256, 0, stream>>>(Abf, Mtb, ybias, y);
}

// Round 16
// 202.378 us; speedup vs baseline: 1.0628x; 1.0628x over previous
//
#include <hip/hip_runtime.h>
#include <math.h>

typedef unsigned short u16;
typedef __attribute__((ext_vector_type(8))) short bffrag;   // 8 bf16 MFMA operand
typedef __attribute__((ext_vector_type(4))) float f32x4;    // MFMA accumulator
typedef __attribute__((ext_vector_type(4))) unsigned short us4;
typedef __attribute__((ext_vector_type(8))) unsigned short us8;

#define SCALE_QK (1.0f/32.0f)

// fp32 -> bf16 round-to-nearest-even (bit trick, NaN-free inputs)
__device__ __forceinline__ u16 f2bf(float f) {
    unsigned u = __builtin_bit_cast(unsigned, f);
    u += 0x7fffu + ((u >> 16) & 1u);
    return (u16)(u >> 16);
}
__device__ __forceinline__ float bf2f(u16 v) {
    unsigned u = ((unsigned)v) << 16;
    return __builtin_bit_cast(float, u);
}

__device__ __forceinline__ void gld16(const u16* g, u16* l) {
    __builtin_amdgcn_global_load_lds(
        (const __attribute__((address_space(1))) void*)g,
        (__attribute__((address_space(3))) void*)l, 16, 0, 0);
}

// ---------------- router (fp32, exact) + c1 partial blocks ----------------
// bids 0..255: cpart[e][hc][d] = sum_{h in hc} bv[e][h]*Wff[e][h][d]  (ungated)
// bids 256..1279: router partial dot-products
__global__ __launch_bounds__(256) void router_c1(const float* __restrict__ X,
                                                 const float* __restrict__ sW,
                                                 float* __restrict__ part,
                                                 const float* __restrict__ Wff,
                                                 const float* __restrict__ bv,
                                                 float* __restrict__ cpart) {
    int bid = blockIdx.x;
    if (bid < 256) {
        int e = bid >> 5;
        int r = bid & 31;
        int d = (r & 3) * 256 + threadIdx.x;
        int h0 = (r >> 2) * 128;
        const float* W = Wff + ((size_t)e << 20) + (size_t)h0 * 1024 + d;
        const float* bvp = bv + e * 1024 + h0;
        float s = 0.f;
        #pragma unroll 4
        for (int h = 0; h < 128; ++h) s += bvp[h] * W[(size_t)h * 1024];
        cpart[(e * 8 + (r >> 2)) * 1024 + d] = s;
        return;
    }
    int rbid = bid - 256;
    float acc[32];
    #pragma unroll
    for (int a = 0; a < 32; ++a) acc[a] = 0.f;
    int tid = rbid * 256 + threadIdx.x;
    #pragma unroll
    for (int q = 0; q < 4; ++q) {
        int i = tid + q * 262144;
        float4 w0 = *(const float4*)(sW + (size_t)i * 8);
        float4 w1 = *(const float4*)(sW + (size_t)i * 8 + 4);
        #pragma unroll
        for (int b = 0; b < 4; ++b) {
            float x = X[((size_t)b << 20) + i];
            acc[b*8+0] += x * w0.x; acc[b*8+1] += x * w0.y;
            acc[b*8+2] += x * w0.z; acc[b*8+3] += x * w0.w;
            acc[b*8+4] += x * w1.x; acc[b*8+5] += x * w1.y;
            acc[b*8+6] += x * w1.z; acc[b*8+7] += x * w1.w;
        }
    }
    __shared__ float wsum[4][32];
    int lane = threadIdx.x & 63, wv = threadIdx.x >> 6;
    #pragma unroll
    for (int a = 0; a < 32; ++a) {
        float v = acc[a];
        #pragma unroll
        for (int off = 32; off; off >>= 1) v += __shfl_down(v, off, 64);
        if (lane == 0) wsum[wv][a] = v;
    }
    __syncthreads();
    int t = threadIdx.x;
    if (t < 32)
        part[(size_t)t * 1024 + rbid] = wsum[0][t] + wsum[1][t] + wsum[2][t] + wsum[3][t];
}

__global__ __launch_bounds__(256) void router_final(const float* __restrict__ part,
                                                    const float* __restrict__ sb,
                                                    int* __restrict__ sel_need) {
    __shared__ float ps[32][8];
    __shared__ float lg[32];
    int t = threadIdx.x, a = t >> 3, c = t & 7;
    {
        float s = 0.f;
        const float* p = part + (size_t)a * 1024 + c * 128;
        for (int i = 0; i < 128; ++i) s += p[i];
        ps[a][c] = s;
    }
    __syncthreads();
    if (t < 32) {
        float v = 0.f;
        #pragma unroll
        for (int j = 0; j < 8; ++j) v += ps[t][j];
        lg[t] = v + sb[t & 7];
    }
    __syncthreads();
    if (t < 4) {
        int base = t * 8;
        int e1 = 0; float v1 = lg[base];
        for (int e = 1; e < 8; ++e) { if (lg[base + e] > v1) { v1 = lg[base + e]; e1 = e; } }
        int e2 = -1; float v2 = -INFINITY;
        for (int e = 0; e < 8; ++e) {
            if (e == e1) continue;
            if (lg[base + e] > v2) { v2 = lg[base + e]; e2 = e; }
        }
        sel_need[t * 2] = e1; sel_need[t * 2 + 1] = e2;
    }
    __syncthreads();
    if (t < 8) {
        int need = 0;
        for (int j = 0; j < 8; ++j) need |= (sel_need[j] == t);
        sel_need[8 + t] = need;
    }
}

// ---------------- unified convert ----------------
// z 0..23: transpose+convert Wq/Wk/Wff (need-gated) — vector global both sides,
//          scalar work on LDS (XOR-swizzled row-major tile, ≤4-way banks)
// z 24..27: plain convert X batch
// z 28..35: plain convert Wv expert (need-gated)
__global__ __launch_bounds__(256) void cvt_all(const float* __restrict__ Wq,
                                               const float* __restrict__ Wk,
                                               const float* __restrict__ Wff,
                                               const float* __restrict__ X,
                                               const float* __restrict__ Wv,
                                               const int* __restrict__ sel_need,
                                               u16* __restrict__ WqT, u16* __restrict__ WkT,
                                               u16* __restrict__ WffT,
                                               u16* __restrict__ Xb, u16* __restrict__ WvB) {
    int z = blockIdx.z;
    int R0 = blockIdx.y * 128, C0 = blockIdx.x * 128;
    int t = threadIdx.x;
    if (z < 24) {
        int type = z >> 3, e = z & 7;
        if (!sel_need[8 + e]) return;
        const float* src = (type == 0 ? Wq : type == 1 ? Wk : Wff) + ((size_t)e << 20);
        u16* dst = (type == 0 ? WqT : type == 1 ? WkT : WffT) + ((size_t)e << 20);
        __shared__ u16 lt[128 * 136];
        // phase 1: float4x2 global reads -> row-major LDS (col ^= ((row>>3)&7)<<3)
        int r = t >> 4;              // 0..15
        int c8 = (t & 15) * 8;       // 0..120
        #pragma unroll
        for (int it = 0; it < 8; ++it) {
            int row = it * 16 + r;
            const float* sp = src + (size_t)(R0 + row) * 1024 + C0 + c8;
            float4 a = *(const float4*)sp;
            float4 b2 = *(const float4*)(sp + 4);
            us8 o;
            o[0] = f2bf(a.x); o[1] = f2bf(a.y); o[2] = f2bf(a.z); o[3] = f2bf(a.w);
            o[4] = f2bf(b2.x); o[5] = f2bf(b2.y); o[6] = f2bf(b2.z); o[7] = f2bf(b2.w);
            int cs = c8 ^ (((row >> 3) & 7) << 3);
            *(us8*)&lt[row * 136 + cs] = o;
        }
        __syncthreads();
        // phase 2: 8 scalar LDS reads -> us8 -> vector global write
        int dd = (t & 15) * 8;       // source-row base (dest col base)
        int hh = t >> 4;             // 0..15
        #pragma unroll
        for (int it = 0; it < 8; ++it) {
            int cr = it * 16 + hh;   // source col = dest row
            us8 o;
            #pragma unroll
            for (int j = 0; j < 8; ++j) {
                int row = dd + j;
                int cs = cr ^ (((row >> 3) & 7) << 3);
                o[j] = lt[row * 136 + cs];
            }
            *(us8*)(dst + (size_t)(C0 + cr) * 1024 + R0 + dd) = o;
        }
    } else {
        const float* src; u16* dst;
        if (z < 28) {
            int b = z - 24;
            src = X + ((size_t)b << 20);  dst = Xb + ((size_t)b << 20);
        } else {
            int e = z - 28;
            if (!sel_need[8 + e]) return;
            src = Wv + ((size_t)e << 20);  dst = WvB + ((size_t)e << 20);
        }
        int r = t >> 4;                  // 0..15
        int c8 = (t & 15) * 8;           // col offset
        #pragma unroll
        for (int it = 0; it < 8; ++it) {
            int row = R0 + it * 16 + r;
            const float* sp = src + (size_t)row * 1024 + C0 + c8;
            float4 a = *(const float4*)sp;
            float4 b2 = *(const float4*)(sp + 4);
            us8 o;
            o[0] = f2bf(a.x); o[1] = f2bf(a.y); o[2] = f2bf(a.z); o[3] = f2bf(a.w);
            o[4] = f2bf(b2.x); o[5] = f2bf(b2.y); o[6] = f2bf(b2.z); o[7] = f2bf(b2.w);
            *(us8*)(dst + (size_t)row * 1024 + C0 + c8) = o;
        }
    }
}

// ============ 8-phase 256x256 MFMA core (T2+T3+T4+T5) — r7 proven schedule ============
__device__ __forceinline__ void stage_half8(const u16* g, int ld, u16* ldst, int tid) {
    int r = tid >> 3;
    int j = ((tid ^ r) & 7) * 8;
    gld16(g + (size_t)r * ld + j, ldst + tid * 8);
    gld16(g + (size_t)(r + 64) * ld + j, ldst + 4096 + tid * 8);
}

template<int Q, bool LASTVM>
__device__ __forceinline__ void phase8(const u16* Ac, const bffrag (&bfr)[4][2],
                                       f32x4 (&acc)[8][4], int rb, int l15, int x0,
                                       const u16* sg, int sld, u16* sdst, int tid) {
    bffrag af[2][2];
    #pragma unroll
    for (int mm = 0; mm < 2; ++mm) {
        int r = (rb + Q * 32 + mm * 16 + l15) * 64;
        af[mm][0] = *(const bffrag*)(Ac + r + x0);
        af[mm][1] = *(const bffrag*)(Ac + r + (x0 ^ 32));
    }
    __builtin_amdgcn_sched_barrier(0);
    stage_half8(sg, sld, sdst, tid);
    __builtin_amdgcn_sched_barrier(0);
    __builtin_amdgcn_s_barrier();
    asm volatile("s_waitcnt lgkmcnt(0)" ::: "memory");
    __builtin_amdgcn_sched_barrier(0);
    __builtin_amdgcn_s_setprio(1);
    #pragma unroll
    for (int ks = 0; ks < 2; ++ks)
        #pragma unroll
        for (int mm = 0; mm < 2; ++mm)
            #pragma unroll
            for (int nn = 0; nn < 4; ++nn)
                acc[Q*2+mm][nn] = __builtin_amdgcn_mfma_f32_16x16x32_bf16(
                    af[mm][ks], bfr[nn][ks], acc[Q*2+mm][nn], 0, 0, 0);
    __builtin_amdgcn_s_setprio(0);
    __builtin_amdgcn_sched_barrier(0);
    if (LASTVM) asm volatile("s_waitcnt vmcnt(4)" ::: "memory");
    __builtin_amdgcn_s_barrier();
}

__device__ __forceinline__ void gemm8(const u16* __restrict__ A, int lda,
                                      const u16* __restrict__ B, int ldb,
                                      int K, int m0, int n0, f32x4 (&acc)[8][4]) {
    __shared__ u16 lds[65536];                 // 128 KB: [buf][A 16384 | B 16384]
    const int tid = threadIdx.x, l = tid & 63, wid = tid >> 6;
    const int wr = wid >> 2, wc = wid & 3;
    const int l15 = l & 15;
    const int rb = wr * 128;                   // wave A-row base
    const int cb = wc * 64;                    // wave B-row base
    const int x0 = (((l >> 4) ^ (l & 7)) * 8); // swizzled k-slot, ks=0 (ks=1: ^32)
    const int nt = K >> 6;

    const u16* Ag = A + (size_t)m0 * lda;
    const u16* Bg = B + (size_t)n0 * ldb;

    // prologue: A(0) halves -> buf0, B(0) -> buf0, B(1) -> buf1
    stage_half8(Ag,                          lda, lds,                 tid);
    stage_half8(Ag + (size_t)128 * lda,      lda, lds + 8192,          tid);
    stage_half8(Bg,                          ldb, lds + 16384,         tid);
    stage_half8(Bg + (size_t)128 * ldb,      ldb, lds + 16384 + 8192,  tid);
    stage_half8(Bg + 64,                     ldb, lds + 32768 + 16384, tid);
    stage_half8(Bg + 64 + (size_t)128 * ldb, ldb, lds + 32768 + 16384 + 8192, tid);
    asm volatile("s_waitcnt vmcnt(4)" ::: "memory");
    __builtin_amdgcn_s_barrier();

    for (int t7 = 0; t7 < nt; ++t7) {
        const int cur = t7 & 1;
        u16* Ac = lds + cur * 32768;
        u16* Bc = Ac + 16384;
        u16* An = lds + (cur ^ 1) * 32768;
        const int ka = (t7 + 1 < nt ? t7 + 1 : nt - 1) << 6;   // A(kt+1) col off
        const int kb = (t7 + 2 < nt ? t7 + 2 : nt - 1) << 6;   // B(kt+2) col off
        const u16* sA0 = Ag + ka;
        const u16* sA1 = Ag + (size_t)128 * lda + ka;
        const u16* sB0 = Bg + kb;
        const u16* sB1 = Bg + (size_t)128 * ldb + kb;

        // B-frags for this K-tile (read in phase 0, used by all 4 phases)
        bffrag bfr[4][2];
        #pragma unroll
        for (int nn = 0; nn < 4; ++nn) {
            int r = (cb + nn * 16 + l15) * 64;
            bfr[nn][0] = *(const bffrag*)(Bc + r + x0);
            bfr[nn][1] = *(const bffrag*)(Bc + r + (x0 ^ 32));
        }
        phase8<0, false>(Ac, bfr, acc, rb, l15, x0, sA0, lda, An, tid);
        phase8<1, false>(Ac, bfr, acc, rb, l15, x0, sA1, lda, An + 8192, tid);
        phase8<2, false>(Ac, bfr, acc, rb, l15, x0, sB0, ldb, Bc, tid);
        phase8<3, true >(Ac, bfr, acc, rb, l15, x0, sB1, ldb, Bc + 8192, tid);
    }
}

__device__ __forceinline__ void zero8(f32x4 (&acc)[8][4]) {
    #pragma unroll
    for (int m = 0; m < 8; ++m)
        #pragma unroll
        for (int n = 0; n < 4; ++n)
            #pragma unroll
            for (int i = 0; i < 4; ++i) acc[m][n][i] = 0.f;
}

// bf16 epilogue with scale + optional col-bias (explicit tile origin)
__device__ __forceinline__ void epi8_bf16(u16* __restrict__ C, int ldc, float scale,
                                          const f32x4 (&acc)[8][4],
                                          const float* __restrict__ biasN,
                                          int M0, int N0) {
    const int tid = threadIdx.x, l = tid & 63, wid = tid >> 6;
    const int wr = wid >> 2, wc = wid & 3;
    const int m0 = M0 + wr * 128, n0 = N0 + wc * 64;
    const int l15 = l & 15, l4 = (l >> 4) * 4;
    #pragma unroll
    for (int mt = 0; mt < 8; ++mt)
        #pragma unroll
        for (int nn = 0; nn < 4; ++nn) {
            int col = n0 + nn * 16 + l15;
            float bn = biasN ? biasN[col] : 0.f;
            #pragma unroll
            for (int i = 0; i < 4; ++i) {
                int row = m0 + mt * 16 + l4 + i;
                C[(size_t)row * ldc + col] = f2bf(acc[mt][nn][i] * scale + bn);
            }
        }
}

// XCD-clustered decode: flat grid 256; XCD k (= f%8) serves z = k and z = k+8.
__device__ __forceinline__ void xcd_decode(int f, int& z, int& m0, int& n0) {
    int xcd = f & 7, slot = f >> 3;
    z = xcd + ((slot >> 4) << 3);
    int idx = slot & 15;
    m0 = (idx >> 2) * 256;
    n0 = (idx & 3) * 256;
}

// D1: z 0..15, w=z>>3 (0=Q,1=K), bs=z&7.  XCD k holds {Q,K} of bs=k (6 MB/L2).
__global__ __launch_bounds__(512) void mfma8_qk(const u16* __restrict__ Xb,
        const u16* __restrict__ WqT, const u16* __restrict__ WkT,
        const float* __restrict__ bq, const float* __restrict__ bk,
        const int* __restrict__ sel, u16* __restrict__ Qb, u16* __restrict__ Kb) {
    int z, m0, n0;
    xcd_decode(blockIdx.x, z, m0, n0);
    int w = z >> 3, bs = z & 7;
    int b = bs >> 1, e = sel[bs];
    f32x4 acc[8][4]; zero8(acc);
    gemm8(Xb + ((size_t)b << 20), 1024, (w ? WkT : WqT) + ((size_t)e << 20), 1024,
          1024, m0, n0, acc);
    epi8_bf16((w ? Kb : Qb) + ((size_t)bs << 20), 1024, 1.0f, acc,
              (w ? bk : bq) + e * 1024, m0, n0);
}

// D2: z<8 scores->Sb (bf16, scaled); z 8..15 wvf halves -> P0b/P1b (bf16)
__global__ __launch_bounds__(512) void mfma8_sw(const u16* __restrict__ Qb,
        const u16* __restrict__ Kb, const u16* __restrict__ WffT,
        const u16* __restrict__ WvB, const int* __restrict__ sel,
        u16* __restrict__ Sb, u16* __restrict__ P0b, u16* __restrict__ P1b) {
    int z, m0, n0;
    xcd_decode(blockIdx.x, z, m0, n0);
    f32x4 acc[8][4]; zero8(acc);
    if (z < 8) {
        gemm8(Qb + ((size_t)z << 20), 1024, Kb + ((size_t)z << 20), 1024, 1024, m0, n0, acc);
        epi8_bf16(Sb + ((size_t)z << 20), 1024, SCALE_QK, acc, nullptr, m0, n0);
    } else {
        int h = (z >= 12), b = z & 3, e = sel[b * 2 + h];
        gemm8(WffT + ((size_t)e << 20), 1024, WvB + ((size_t)e << 20), 1024, 1024, m0, n0, acc);
        epi8_bf16((h ? P1b : P0b) + ((size_t)b << 20), 1024, 1.0f, acc, nullptr, m0, n0);
    }
}

// Wvfsum[b] = bf16(P0b[b] + P1b[b]);  bids >= 2048: ybias blocks (cpart-based, cheap)
__global__ __launch_bounds__(256) void wvfadd(const u16* __restrict__ P0b,
                                              const u16* __restrict__ P1b,
                                              u16* __restrict__ W,
                                              const float* __restrict__ cpart,
                                              const float* __restrict__ bff,
                                              const int* __restrict__ sel,
                                              float* __restrict__ ybias) {
    int bid = blockIdx.x;
    if (bid >= 2048) {
        int r = bid - 2048;              // 0..15
        int b = r >> 2;
        int d = (r & 3) * 256 + threadIdx.x;
        int e0 = sel[b * 2], e1 = sel[b * 2 + 1];
        float c0 = 0.f, c1v = 0.f;
        #pragma unroll
        for (int hc = 0; hc < 8; ++hc) {
            c0  += cpart[(e0 * 8 + hc) * 1024 + d];
            c1v += cpart[(e1 * 8 + hc) * 1024 + d];
        }
        ybias[b * 1024 + d] = 2.f * (c0 + c1v) + bff[e0 * 1024 + d] + bff[e1 * 1024 + d];
        return;
    }
    size_t i = (size_t)(bid * 256 + threadIdx.x) * 8;
    us8 a = *(const us8*)(P0b + i);
    us8 b = *(const us8*)(P1b + i);
    us8 o;
    #pragma unroll
    for (int j = 0; j < 8; ++j) o[j] = f2bf(bf2f(a[j]) + bf2f(b[j]));
    *(us8*)(W + i) = o;
}

// ---------------- 2-phase 128x128 core (tail GEMMs; explicit m0/n0) ----------------
__device__ __forceinline__ void stage_tile(const u16* a0, const u16* a1,
                                           const u16* b0, const u16* b1,
                                           u16* sa, u16* sb, int tid) {
    gld16(a0, &sa[tid * 8]);
    gld16(a1, &sa[2048 + tid * 8]);
    gld16(b0, &sb[tid * 8]);
    gld16(b1, &sb[2048 + tid * 8]);
}

__device__ __forceinline__ void gemm_ds(const u16* __restrict__ A, int lda,
                                        const u16* __restrict__ B, int ldb,
                                        int K, int m0, int n0, f32x4 (&acc)[4][4]) {
    __shared__ u16 sA[2][4096];
    __shared__ u16 sB[2][4096];
    const int tid = threadIdx.x, lane = tid & 63, wv = tid >> 6;
    const int wr = (wv >> 1) * 64, wc = (wv & 1) * 64;
    const int l15 = lane & 15, lk = (lane >> 4) * 8;
    const int r0 = tid >> 2, k8 = (tid & 3) * 8;

    const u16* a0 = A + (size_t)(m0 + r0) * lda + k8;
    const u16* a1 = A + (size_t)(m0 + 64 + r0) * lda + k8;
    const u16* b0 = B + (size_t)(n0 + r0) * ldb + k8;
    const u16* b1 = B + (size_t)(n0 + 64 + r0) * ldb + k8;

    stage_tile(a0, a1, b0, b1, sA[0], sB[0], tid);
    __syncthreads();

    const int nt = K >> 5;
    for (int t = 0; t < nt; ++t) {
        const int cur = t & 1;
        if (t + 1 < nt) {
            int k0 = (t + 1) << 5;
            stage_tile(a0 + k0, a1 + k0, b0 + k0, b1 + k0, sA[cur ^ 1], sB[cur ^ 1], tid);
        }
        bffrag av[4], bf[4];
        #pragma unroll
        for (int m = 0; m < 4; ++m)
            av[m] = *reinterpret_cast<const bffrag*>(&sA[cur][(wr + m * 16 + l15) * 32 + lk]);
        #pragma unroll
        for (int n = 0; n < 4; ++n)
            bf[n] = *reinterpret_cast<const bffrag*>(&sB[cur][(wc + n * 16 + l15) * 32 + lk]);
        #pragma unroll
        for (int m = 0; m < 4; ++m)
            #pragma unroll
            for (int n = 0; n < 4; ++n)
                acc[m][n] = __builtin_amdgcn_mfma_f32_16x16x32_bf16(av[m], bf[n], acc[m][n], 0, 0, 0);
        __syncthreads();
    }
}

__device__ __forceinline__ void zero_acc(f32x4 (&acc)[4][4]) {
    #pragma unroll
    for (int m = 0; m < 4; ++m)
        #pragma unroll
        for (int n = 0; n < 4; ++n)
            #pragma unroll
            for (int i = 0; i < 4; ++i) acc[m][n][i] = 0.f;
}

__device__ __forceinline__ void epi4_bf16(u16* __restrict__ C, int ldc, int m0, int n0,
                                          const f32x4 (&acc)[4][4]) {
    const int tid = threadIdx.x, lane = tid & 63, wv = tid >> 6;
    const int wr = (wv >> 1) * 64, wc = (wv & 1) * 64;
    const int l15 = lane & 15, l4 = (lane >> 4) * 4;
    #pragma unroll
    for (int m = 0; m < 4; ++m)
        #pragma unroll
        for (int n = 0; n < 4; ++n) {
            int col = n0 + wc + n * 16 + l15;
            #pragma unroll
            for (int i = 0; i < 4; ++i) {
                int row = m0 + wr + m * 16 + l4 + i;
                C[(size_t)row * ldc + col] = f2bf(acc[m][n][i]);
            }
        }
}

__device__ __forceinline__ void epi4_f32(float* __restrict__ C, int ldc, int m0, int n0,
                                         const f32x4 (&acc)[4][4],
                                         const float* __restrict__ bias1) {
    const int tid = threadIdx.x, lane = tid & 63, wv = tid >> 6;
    const int wr = (wv >> 1) * 64, wc = (wv & 1) * 64;
    const int l15 = lane & 15, l4 = (lane >> 4) * 4;
    #pragma unroll
    for (int m = 0; m < 4; ++m)
        #pragma unroll
        for (int n = 0; n < 4; ++n) {
            int col = n0 + wc + n * 16 + l15;
            float bn = bias1 ? bias1[col] : 0.f;
            #pragma unroll
            for (int i = 0; i < 4; ++i) {
                int row = m0 + wr + m * 16 + l4 + i;
                C[(size_t)row * ldc + col] = acc[m][n][i] + bn;
            }
        }
}

// ---------------- merged: Mt GEMM (bids 0..255) + softmax-combine (bids 256..4351) ----------------
__global__ __launch_bounds__(256) void sm_mt(const u16* __restrict__ Sb, u16* __restrict__ Ab,
        const u16* __restrict__ Wvfsum, const u16* __restrict__ Xb, u16* __restrict__ Mtb) {
    int bid = blockIdx.x;
    if (bid < 256) {
        int b = bid >> 6, m0 = ((bid >> 3) & 7) * 128, n0 = (bid & 7) * 128;
        f32x4 acc[4][4]; zero_acc(acc);
        gemm_ds(Wvfsum + ((size_t)b << 20), 1024, Xb + ((size_t)b << 20), 1024, 1024, m0, n0, acc);
        epi4_bf16(Mtb + ((size_t)b << 20), 1024, m0, n0, acc);
        return;
    }
    int bs = bid - 256, b = bs >> 10, s = bs & 1023;
    const u16* S0 = Sb + ((size_t)(b * 2) << 20) + (size_t)s * 1024;
    const u16* S1 = S0 + (1u << 20);
    int t = threadIdx.x, lane = t & 63, wv = t >> 6;
    us4 xv0 = *(const us4*)(S0 + t * 4);
    us4 xv1 = *(const us4*)(S1 + t * 4);
    float x0[4], x1[4];
    #pragma unroll
    for (int j = 0; j < 4; ++j) { x0[j] = bf2f(xv0[j]); x1[j] = bf2f(xv1[j]); }
    float m0 = fmaxf(fmaxf(x0[0], x0[1]), fmaxf(x0[2], x0[3]));
    float m1 = fmaxf(fmaxf(x1[0], x1[1]), fmaxf(x1[2], x1[3]));
    #pragma unroll
    for (int off = 32; off; off >>= 1) {
        m0 = fmaxf(m0, __shfl_xor(m0, off, 64));
        m1 = fmaxf(m1, __shfl_xor(m1, off, 64));
    }
    __shared__ float wred[4][4];
    if (lane == 0) { wred[wv][0] = m0; wred[wv][1] = m1; }
    __syncthreads();
    m0 = fmaxf(fmaxf(wred[0][0], wred[1][0]), fmaxf(wred[2][0], wred[3][0]));
    m1 = fmaxf(fmaxf(wred[0][1], wred[1][1]), fmaxf(wred[2][1], wred[3][1]));
    float e0[4], e1[4];
    #pragma unroll
    for (int j = 0; j < 4; ++j) { e0[j] = __expf(x0[j] - m0); e1[j] = __expf(x1[j] - m1); }
    float s0 = e0[0] + e0[1] + e0[2] + e0[3];
    float s1 = e1[0] + e1[1] + e1[2] + e1[3];
    #pragma unroll
    for (int off = 32; off; off >>= 1) {
        s0 += __shfl_xor(s0, off, 64);
        s1 += __shfl_xor(s1, off, 64);
    }
    if (lane == 0) { wred[wv][2] = s0; wred[wv][3] = s1; }
    __syncthreads();
    s0 = wred[0][2] + wred[1][2] + wred[2][2] + wred[3][2];
    s1 = wred[0][3] + wred[1][3] + wred[2][3] + wred[3][3];
    float r0 = 1.f / s0, r1 = 1.f / s1;
    us4 o;
    #pragma unroll
    for (int j = 0; j < 4; ++j) o[j] = f2bf(e0[j] * r0 + e1[j] * r1);
    *(us4*)(Ab + ((size_t)b << 20) + (size_t)s * 1024 + t * 4) = o;
}

// y[b][s][d2] = sum_t A[b][s][t] * Mt[b][d2][t] + ybias[b][d2]
__global__ __launch_bounds__(256) void mfma_y(const u16* __restrict__ Abf,
        const u16* __restrict__ Mtb, const float* __restrict__ ybias,
        float* __restrict__ y) {
    int b = blockIdx.z;
    int m0 = blockIdx.y * 128, n0 = blockIdx.x * 128;
    f32x4 acc[4][4]; zero_acc(acc);
    gemm_ds(Abf + ((size_t)b << 20), 1024, Mtb + ((size_t)b << 20), 1024, 1024, m0, n0, acc);
    epi4_f32(y + ((size_t)b << 20), 1024, m0, n0, acc, ybias + b * 1024);
}

// ---------------- launcher ----------------
extern "C" void kernel_launch(void* const* d_in, const int* in_sizes, int n_in,
                              void* d_out, int out_size, void* d_ws, size_t ws_size,
                              hipStream_t stream) {
    const float* X   = (const float*)d_in[0];
    const float* sW  = (const float*)d_in[2];
    const float* sb  = (const float*)d_in[3];
    const float* Wq  = (const float*)d_in[4];
    const float* bq  = (const float*)d_in[5];
    const float* Wk  = (const float*)d_in[6];
    const float* bk  = (const float*)d_in[7];
    const float* Wv  = (const float*)d_in[8];
    const float* bv  = (const float*)d_in[9];
    const float* Wff = (const float*)d_in[10];
    const float* bff = (const float*)d_in[11];
    float* y = (float*)d_out;

    char* w = (char*)d_ws;
    float* part  = (float*)w;                  // 128 KB
    float* cpart = (float*)(w + (1u << 17));   // 256 KB (concurrent with part)
    int*   sel   = (int*)(w + 393216);         // at 384 KB
    float* ybias = (float*)(w + 393216 + 256); // 16 KB
    u16* base = (u16*)(w + (1u << 19));        // at 512 KB
    u16* Xb   = base;                          // 8 MB
    u16* WqT  = Xb   + (4u << 20);             // 16 MB  [Abf overlay]
    u16* WkT  = WqT  + (8u << 20);             // 16 MB  [Mtb overlay]
    u16* WffT = WkT  + (8u << 20);             // 16 MB
    u16* WvB  = WffT + (8u << 20);             // 16 MB
    u16* Qb   = WvB  + (8u << 20);             // 16 MB  [Wvfsum overlay]
    u16* Kb   = Qb   + (8u << 20);             // 16 MB
    u16* Sb   = Kb   + (8u << 20);             // 16 MB (bf16 scores, 8 x 1M)
    u16* P0b  = Sb   + (8u << 20);             // 8 MB
    u16* P1b  = P0b  + (4u << 20);             // 8 MB
    u16* Abf    = WqT;   // WqT dead after mfma8_qk
    u16* Mtb    = WkT;   // WkT dead after mfma8_qk
    u16* Wvfsum = Qb;    // Qb dead after mfma8_sw

    router_c1<<<1280, 256, 0, stream>>>(X, sW, part, Wff, bv, cpart);
    router_final<<<1, 256, 0, stream>>>(part, sb, sel);
    cvt_all<<<dim3(8, 8, 36), 256, 0, stream>>>(Wq, Wk, Wff, X, Wv, sel,
                                                WqT, WkT, WffT, Xb, WvB);

    mfma8_qk<<<256, 512, 0, stream>>>(Xb, WqT, WkT, bq, bk, sel, Qb, Kb);
    mfma8_sw<<<256, 512, 0, stream>>>(Qb, Kb, WffT, WvB, sel, Sb, P0b, P1b);
    wvfadd<<<2064, 256, 0, stream>>>(P0b, P1b, Wvfsum, cpart, bff, sel, ybias);
    sm_mt<<<4352, 256, 0, stream>>>(Sb, Abf, Wvfsum, Xb, Mtb);
    mfma_y<<<dim3(8, 8, 4), 256, 0, stream>>>(Abf, Mtb, ybias, y);
}